// Round 3
// baseline (143.706 us; speedup 1.0000x reference)
//
#include <hip/hip_runtime.h>
#include <cstdint>

#define BB 4
#define NN 1024
#define DD 32
#define NWORDS 16           // NN / 64
#define RPB 16              // rows per block
#define NEG_INF_F (-1e10f)

// Fully fused single kernel. 64 blocks per batch, 16 rows each, 256 threads.
// reach[i,k] = OR_{j: e[i,j]=1} e[j,k]  (STEP_NUM=2, no +edges term).
// With density-0.5 random adjacency, ORing the ~32 neighbor rows among
// j<64 saturates every 64-bit word of reach with prob 1 - ~1.5e-8, so the
// common path needs only edges[b,0:64,:] (packed tile, 8 KB LDS) and
// edges[b,i,0:64] (neighbor word 0) -- 512 KB/batch instead of 16.8 MB.
// Saturated rows output the per-batch feature column-max. Unsaturated rows
// (prob ~0) take an exact slow fallback straight from edges.
__global__ __launch_bounds__(256) void fused_kernel(
        const float* __restrict__ feat,
        const int*   __restrict__ edges,
        float*       __restrict__ out) {
    const int blk  = blockIdx.x;            // 64 blocks per batch
    const int b    = blk >> 6;
    const int r0   = (blk & 63) * RPB;      // first row within batch
    const int t    = threadIdx.x;
    const int lane = t & 63;
    const int wave = t >> 6;
    const int il   = t >> 4;                // local row 0..15
    const int w    = t & 15;                // mask word 0..15

    __shared__ unsigned long long s_tile[64 * NWORDS];  // 8 KB: rows 0..63 packed
    __shared__ unsigned long long s_rw[RPB];            // neighbor word 0 per row
    __shared__ int    s_need[RPB];
    __shared__ float4 s_red[32 * 8];                    // colmax partials, 4 KB
    __shared__ float  s_cmax[DD];
    // fallback-only:
    __shared__ int           s_ei[NN];                  // 4 KB
    __shared__ unsigned char s_reach[NN];
    __shared__ float s_m[256], s_u[256];

    if (t < RPB) s_need[t] = 0;

    // ---- phase 0: per-batch column-max of features (float4 loads) ----
    {
        const float4* fb4 = reinterpret_cast<const float4*>(feat + (size_t)b * NN * DD);
        const int d4 = t & 7;               // which float4 of the 8 per row
        const int kc = t >> 3;              // 32 chunks of 32 rows
        float4 m = make_float4(-INFINITY, -INFINITY, -INFINITY, -INFINITY);
#pragma unroll 8
        for (int kk = 0; kk < 32; ++kk) {
            const float4 v = fb4[(size_t)(kc * 32 + kk) * 8 + d4];
            m.x = fmaxf(m.x, v.x); m.y = fmaxf(m.y, v.y);
            m.z = fmaxf(m.z, v.z); m.w = fmaxf(m.w, v.w);
        }
        s_red[kc * 8 + d4] = m;
    }
    __syncthreads();
    for (int s = 16; s > 0; s >>= 1) {
        if (t < s * 8) {
            const int kc = t >> 3, d4 = t & 7;
            float4 a = s_red[kc * 8 + d4];
            const float4 c = s_red[(kc + s) * 8 + d4];
            a.x = fmaxf(a.x, c.x); a.y = fmaxf(a.y, c.y);
            a.z = fmaxf(a.z, c.z); a.w = fmaxf(a.w, c.w);
            s_red[kc * 8 + d4] = a;
        }
        __syncthreads();
    }
    if (t < 8) reinterpret_cast<float4*>(s_cmax)[t] = s_red[t];

    // ---- phase 1: pack tile = edges[b, 0:64, :] via ballot ----
    const int* eb = edges + (size_t)b * NN * NN;
    for (int rr = wave; rr < 64; rr += 4) {
        const int* er = eb + (size_t)rr * NN + lane;
#pragma unroll
        for (int ww = 0; ww < NWORDS; ++ww) {
            const unsigned long long bm = __ballot(er[ww * 64] != 0);
            if (lane == 0) s_tile[rr * NWORDS + ww] = bm;
        }
    }

    // ---- phase 2: neighbor word 0 for my 16 rows ----
    for (int q = wave * 4; q < wave * 4 + 4; ++q) {
        const unsigned long long bm =
            __ballot(eb[(size_t)(r0 + q) * NN + lane] != 0);
        if (lane == 0) s_rw[q] = bm;
    }
    __syncthreads();

    // ---- phase 3: branchless OR scan (64 independent LDS loads) ----
    {
        const unsigned long long nb = s_rw[il];
        unsigned long long acc = 0ull;
#pragma unroll
        for (int j = 0; j < 64; ++j) {
            const unsigned long long msk = 0ull - ((nb >> j) & 1ull);
            acc |= s_tile[j * NWORDS + w] & msk;
        }
        if (acc != ~0ull) atomicAdd(&s_need[il], 1);
    }
    __syncthreads();

    // ---- phase 4: fast-path output (colmax broadcast) ----
    float* orow_base = out + (size_t)(b * NN + r0) * DD;
    if (s_need[il] == 0) {
        reinterpret_cast<float2*>(orow_base + il * DD)[w] =
            reinterpret_cast<const float2*>(s_cmax)[w];
    }

    // ---- fallback (prob ~0): exact recompute from edges ----
    bool any = false;
    for (int r = 0; r < RPB; ++r) any = any || (s_need[r] != 0);
    if (!any) return;

    for (int r = 0; r < RPB; ++r) {
        if (s_need[r] == 0) continue;       // uniform
        const int i = r0 + r;
        const int* ei = eb + (size_t)i * NN;
#pragma unroll
        for (int q = 0; q < 4; ++q) s_ei[t + q * 256] = ei[t + q * 256];
        __syncthreads();
#pragma unroll
        for (int kq = 0; kq < 4; ++kq) {
            const int k = t * 4 + kq;
            int reach = 0;
            for (int j = 0; j < NN; ++j) {
                if (s_ei[j] != 0 && eb[(size_t)j * NN + k] != 0) { reach = 1; break; }
            }
            s_reach[k] = (unsigned char)reach;
        }
        __syncthreads();
        const int d   = t & 31;
        const int kc8 = t >> 5;
        const float* fb = feat + (size_t)b * NN * DD;
        float mm = -INFINITY, um = -INFINITY;
        for (int kk = 0; kk < 128; ++kk) {
            const int k = kc8 * 128 + kk;
            const float f = fb[(size_t)k * DD + d];
            if (s_reach[k]) mm = fmaxf(mm, f); else um = fmaxf(um, f);
        }
        s_m[t] = mm; s_u[t] = um;
        __syncthreads();
        for (int s = 4; s > 0; s >>= 1) {
            if (kc8 < s) {
                s_m[kc8 * 32 + d] = fmaxf(s_m[kc8 * 32 + d], s_m[(kc8 + s) * 32 + d]);
                s_u[kc8 * 32 + d] = fmaxf(s_u[kc8 * 32 + d], s_u[(kc8 + s) * 32 + d]);
            }
            __syncthreads();
        }
        if (kc8 == 0)
            out[(size_t)(b * NN + i) * DD + d] = fmaxf(s_m[d], s_u[d] + NEG_INF_F);
        __syncthreads();
    }
}

extern "C" void kernel_launch(void* const* d_in, const int* in_sizes, int n_in,
                              void* d_out, int out_size, void* d_ws, size_t ws_size,
                              hipStream_t stream) {
    const float* feat  = (const float*)d_in[0];   // [B,N,D] f32
    const int*   edges = (const int*)d_in[1];     // [B,N,N] i32
    float*       out   = (float*)d_out;           // [B,N,D] f32
    fused_kernel<<<BB * NN / RPB, 256, 0, stream>>>(feat, edges, out);
}

// Round 4
// 67.805 us; speedup vs baseline: 2.1194x; 2.1194x over previous
//
#include <hip/hip_runtime.h>
#include <cstdint>

#define BB 4
#define NN 1024
#define DD 32
#define NWORDS 16           // NN / 64
#define RPB 16              // rows per pool block
#define NEG_INF_F (-1e10f)

typedef unsigned long long u64;

// ws layout:
//   tile_ws : [BB][64][NWORDS] u64   (32 KB)  packed edges[b, 0:64, :]
//   word0_ws: [BB*NN] u64            (32 KB)  packed edges[row, 0:64]
//   cpart_ws: [BB][16][DD] f32       ( 8 KB)  colmax partials (64 rows each)
#define TILE_OFF  0
#define WORD0_OFF (BB * 64 * NWORDS)            // in u64 units
#define CPART_OFF ((BB * 64 * NWORDS + BB * NN) * 2)   // in f32 units (u64=2 f32)

// Kernel 1: all packing + colmax partials. Every thread issues exactly 1-2
// independent vector loads (no load feeding a cross-lane op) so nothing
// serializes on vmcnt. 576 blocks.
__global__ __launch_bounds__(256, 1) void prep_kernel(
        const float* __restrict__ feat,
        const int*   __restrict__ edges,
        u64*         __restrict__ ws64,
        float*       __restrict__ wsf) {
    const int blk = blockIdx.x;
    const int t   = threadIdx.x;

    __shared__ u64 s_word[NWORDS];
    __shared__ __align__(16) float4 s_red[32 * 8];

    if (blk < 256) {
        // ---- pack tile row: batch b = blk>>6, row rr = blk&63 ----
        // thread t covers columns 4t..4t+3 via one int4 load.
        const int4 v = reinterpret_cast<const int4*>(
            edges + (size_t)blk * NN /* = (b*NN + rr)*NN / NN ... blk = b*64+rr, global row = b*1024+rr */
        )[0];
        // NOTE: global row index is b*1024 + rr = (blk>>6)*1024 + (blk&63)
        const size_t grow = (size_t)(blk >> 6) * NN + (blk & 63);
        const int4 vv = reinterpret_cast<const int4*>(edges + grow * NN)[t];
        (void)v;
        const unsigned nib = (vv.x != 0 ? 1u : 0u) | (vv.y != 0 ? 2u : 0u)
                           | (vv.z != 0 ? 4u : 0u) | (vv.w != 0 ? 8u : 0u);
        if (t < NWORDS) s_word[t] = 0ull;
        __syncthreads();
        atomicOr(&s_word[t >> 4], (u64)nib << ((t & 15) * 4));
        __syncthreads();
        if (t < NWORDS) ws64[TILE_OFF + blk * NWORDS + t] = s_word[t];
    } else if (blk < 512) {
        // ---- pack word0 (columns 0..63) for 16 rows ----
        const int idx  = blk - 256;             // 0..255
        const int grow = idx * 16 + (t >> 4);   // global row
        const int4 vv = reinterpret_cast<const int4*>(
            edges + (size_t)grow * NN)[t & 15];
        const unsigned nib = (vv.x != 0 ? 1u : 0u) | (vv.y != 0 ? 2u : 0u)
                           | (vv.z != 0 ? 4u : 0u) | (vv.w != 0 ? 8u : 0u);
        if (t < NWORDS) s_word[t] = 0ull;
        __syncthreads();
        atomicOr(&s_word[t >> 4], (u64)nib << ((t & 15) * 4));
        __syncthreads();
        if (t < NWORDS) ws64[WORD0_OFF + idx * 16 + t] = s_word[t];
    } else {
        // ---- colmax partial: p = blk-512 in [0,64); 64 feature rows ----
        const int p    = blk - 512;
        const int b    = p >> 4;
        const int part = p & 15;
        const float4* fb4 = reinterpret_cast<const float4*>(
            feat + (size_t)b * NN * DD);
        const int d4 = t & 7;
        const int kc = t >> 3;                  // 32 chunks of 2 rows
        float4 m = make_float4(-INFINITY, -INFINITY, -INFINITY, -INFINITY);
#pragma unroll
        for (int kk = 0; kk < 2; ++kk) {
            const float4 v2 = fb4[(size_t)(part * 64 + kc * 2 + kk) * 8 + d4];
            m.x = fmaxf(m.x, v2.x); m.y = fmaxf(m.y, v2.y);
            m.z = fmaxf(m.z, v2.z); m.w = fmaxf(m.w, v2.w);
        }
        s_red[kc * 8 + d4] = m;
        __syncthreads();
        for (int s = 16; s > 0; s >>= 1) {
            if (t < s * 8) {
                float4 a = s_red[t];
                const float4 c = s_red[t + s * 8];
                a.x = fmaxf(a.x, c.x); a.y = fmaxf(a.y, c.y);
                a.z = fmaxf(a.z, c.z); a.w = fmaxf(a.w, c.w);
                s_red[t] = a;
            }
            __syncthreads();
        }
        if (t < 8)
            reinterpret_cast<float4*>(wsf + CPART_OFF + (b * 16 + part) * DD)[t]
                = s_red[t];
    }
}

// Kernel 2: 256 blocks x 256 threads, 16 rows each.
// Branchless OR scan over the LDS tile; saturated words => colmax output.
// Exact fallback recomputes reachability straight from edges (prob ~0).
__global__ __launch_bounds__(256, 1) void pool_kernel(
        const float* __restrict__ feat,
        const int*   __restrict__ edges,
        const u64*   __restrict__ ws64,
        const float* __restrict__ wsf,
        float*       __restrict__ out) {
    const int blk = blockIdx.x;
    const int b   = blk >> 6;
    const int r0  = (blk & 63) * RPB;
    const int t   = threadIdx.x;
    const int il  = t >> 4;
    const int w   = t & 15;

    __shared__ __align__(16) u64 s_tile[64 * NWORDS];   // 8 KB
    __shared__ u64   s_rw[RPB];
    __shared__ int   s_need[RPB];
    __shared__ float s_part[256];
    // fallback-only:
    __shared__ int           s_ei[NN];
    __shared__ unsigned char s_reach[NN];
    __shared__ float s_m[256], s_u[256];

    if (t < RPB) s_need[t] = 0;

    // stage tile (8 KB) via two independent 16B loads per thread
    {
        const longlong2* tb = reinterpret_cast<const longlong2*>(
            ws64 + TILE_OFF + (size_t)b * 64 * NWORDS);
        reinterpret_cast<longlong2*>(s_tile)[t]       = tb[t];
        reinterpret_cast<longlong2*>(s_tile)[t + 256] = tb[t + 256];
    }
    // neighbor word0 for my 16 rows
    if (t < RPB) s_rw[t] = ws64[WORD0_OFF + b * NN + r0 + t];
    // colmax: reduce the 16 partials (512 floats) to 32
    {
        const float* cp = wsf + CPART_OFF + (size_t)b * 16 * DD;
        s_part[t] = fmaxf(cp[t], cp[t + 256]);
    }
    __syncthreads();
    for (int s = 128; s >= 32; s >>= 1) {
        if (t < s) s_part[t] = fmaxf(s_part[t], s_part[t + s]);
        __syncthreads();
    }
    // s_part[0..31] == per-batch column max

    // branchless OR scan: 64 independent LDS loads
    {
        const u64 nb = s_rw[il];
        u64 acc = 0ull;
#pragma unroll
        for (int j = 0; j < 64; ++j) {
            const u64 msk = 0ull - ((nb >> j) & 1ull);
            acc |= s_tile[j * NWORDS + w] & msk;
        }
        if (acc != ~0ull) atomicAdd(&s_need[il], 1);
    }
    __syncthreads();

    // fast path: broadcast colmax
    float* orow_base = out + (size_t)(b * NN + r0) * DD;
    if (s_need[il] == 0) {
        reinterpret_cast<float2*>(orow_base + il * DD)[w] =
            reinterpret_cast<const float2*>(s_part)[w];
    }

    bool any = false;
    for (int r = 0; r < RPB; ++r) any = any || (s_need[r] != 0);
    if (!any) return;

    // ---- exact fallback (prob ~0) ----
    const int* eb = edges + (size_t)b * NN * NN;
    for (int r = 0; r < RPB; ++r) {
        if (s_need[r] == 0) continue;           // block-uniform
        const int i = r0 + r;
        const int* ei = eb + (size_t)i * NN;
#pragma unroll
        for (int q = 0; q < 4; ++q) s_ei[t + q * 256] = ei[t + q * 256];
        __syncthreads();
#pragma unroll
        for (int kq = 0; kq < 4; ++kq) {
            const int k = t * 4 + kq;
            int reach = 0;
            for (int j = 0; j < NN; ++j) {
                if (s_ei[j] != 0 && eb[(size_t)j * NN + k] != 0) { reach = 1; break; }
            }
            s_reach[k] = (unsigned char)reach;
        }
        __syncthreads();
        const int d   = t & 31;
        const int kc8 = t >> 5;
        const float* fb = feat + (size_t)b * NN * DD;
        float mm = -INFINITY, um = -INFINITY;
        for (int kk = 0; kk < 128; ++kk) {
            const int k = kc8 * 128 + kk;
            const float f = fb[(size_t)k * DD + d];
            if (s_reach[k]) mm = fmaxf(mm, f); else um = fmaxf(um, f);
        }
        s_m[t] = mm; s_u[t] = um;
        __syncthreads();
        for (int s = 4; s > 0; s >>= 1) {
            if (kc8 < s) {
                s_m[kc8 * 32 + d] = fmaxf(s_m[kc8 * 32 + d], s_m[(kc8 + s) * 32 + d]);
                s_u[kc8 * 32 + d] = fmaxf(s_u[kc8 * 32 + d], s_u[(kc8 + s) * 32 + d]);
            }
            __syncthreads();
        }
        if (kc8 == 0)
            out[(size_t)(b * NN + i) * DD + d] = fmaxf(s_m[d], s_u[d] + NEG_INF_F);
        __syncthreads();
    }
}

extern "C" void kernel_launch(void* const* d_in, const int* in_sizes, int n_in,
                              void* d_out, int out_size, void* d_ws, size_t ws_size,
                              hipStream_t stream) {
    const float* feat  = (const float*)d_in[0];   // [B,N,D] f32
    const int*   edges = (const int*)d_in[1];     // [B,N,N] i32
    float*       out   = (float*)d_out;           // [B,N,D] f32
    u64*   ws64 = (u64*)d_ws;
    float* wsf  = (float*)d_ws;

    prep_kernel<<<576, 256, 0, stream>>>(feat, edges, ws64, wsf);
    pool_kernel<<<BB * NN / RPB, 256, 0, stream>>>(feat, edges, ws64, wsf, out);
}